// Round 1
// baseline (722.950 us; speedup 1.0000x reference)
//
#include <hip/hip_runtime.h>
#include <math.h>

#define NSLOPE 0.2f

__device__ __forceinline__ void atomicMaxFloat(float* addr, float val) {
    // positive floats order like ints; negative floats order reversed as uints
    if (val >= 0.0f) atomicMax((int*)addr, __float_as_int(val));
    else             atomicMin((unsigned int*)addr, __float_as_uint(val));
}

// K0: init out accumulator to 0, per-node max to -inf, per-node sum to 0
__global__ __launch_bounds__(256) void k0_init(float* __restrict__ out,
                                               float* __restrict__ nmax,
                                               float* __restrict__ nsum,
                                               int n, int nf) {
    int i = blockIdx.x * 256 + threadIdx.x;
    if (i < nf) out[i] = 0.0f;
    if (i < n) { nmax[i] = -INFINITY; nsum[i] = 0.0f; }
}

// K1: h = feat @ W_fc  (N x 128 @ 128 x 64), fused pp = h @ W_post + b_post
// block = 256 threads = 4 waves; 16 rows/block (4 rows per wave); col = lane
__global__ __launch_bounds__(256) void k1_proj(
    const float* __restrict__ feat, const float* __restrict__ wfc,
    const float* __restrict__ wpost, const float* __restrict__ bpost,
    float* __restrict__ h, float4* __restrict__ pp, int n)
{
    __shared__ float wfc_s[128 * 64];   // 32 KB
    __shared__ float feat_s[16 * 128];  // 8 KB
    int t = threadIdx.x;
    // stage W_fc (8192 floats) as float4
    for (int i = t; i < 128 * 64 / 4; i += 256)
        ((float4*)wfc_s)[i] = ((const float4*)wfc)[i];
    int row0 = blockIdx.x * 16;
    // stage 16 feat rows (2048 floats) as float4
    {
        const float4* fv = (const float4*)(feat + (long)row0 * 128);
        int lim = (n - row0) * (128 / 4);
        if (lim > 16 * 128 / 4) lim = 16 * 128 / 4;
        for (int i = t; i < lim; i += 256)
            ((float4*)feat_s)[i] = fv[i];
    }
    __syncthreads();
    int lane = t & 63, wv = t >> 6;
    const float* fr = feat_s + wv * 4 * 128;
    float acc[4] = {0.f, 0.f, 0.f, 0.f};
    #pragma unroll 4
    for (int k = 0; k < 128; k++) {
        float w = wfc_s[k * 64 + lane];   // consecutive lanes -> 2-way alias, free
        #pragma unroll
        for (int r = 0; r < 4; r++) acc[r] += fr[r * 128 + k] * w;  // broadcast
    }
    int r0 = row0 + wv * 4;
    #pragma unroll
    for (int r = 0; r < 4; r++)
        if (r0 + r < n) h[(long)(r0 + r) * 64 + lane] = acc[r];
    // pp epilogue: each wave holds full row across 64 lanes
    float4 wp = ((const float4*)wpost)[lane];   // W_post[lane][0..3]
    float4 bp = *((const float4*)bpost);
    #pragma unroll
    for (int r = 0; r < 4; r++) {
        float cx = acc[r] * wp.x, cy = acc[r] * wp.y,
              cz = acc[r] * wp.z, cw = acc[r] * wp.w;
        #pragma unroll
        for (int off = 32; off > 0; off >>= 1) {
            cx += __shfl_down(cx, off);
            cy += __shfl_down(cy, off);
            cz += __shfl_down(cz, off);
            cw += __shfl_down(cw, off);
        }
        if (lane == 0 && r0 + r < n) {
            float4 o;
            o.x = cx + bp.x; o.y = cy + bp.y; o.z = cz + bp.z; o.w = cw + bp.w;
            pp[r0 + r] = o;
        }
    }
}

// K2: per-edge pre-softmax value e = leakyrelu(loc_l[s]+loc_r[d]) + exp(lsl[s]+lsr[d])*noise
// + segment max over dst via atomicMaxFloat
__global__ __launch_bounds__(256) void k2_edge(
    const int* __restrict__ src, const int* __restrict__ dst,
    const float* __restrict__ noise, const float4* __restrict__ pp,
    float* __restrict__ ew, float* __restrict__ nmax, int E)
{
    int e = blockIdx.x * 256 + threadIdx.x;
    if (e >= E) return;
    int s = src[e], d = dst[e];
    float4 ps = pp[s], pd = pp[d];
    float loc = ps.x + pd.y;                 // loc_l[src] + loc_r[dst]
    loc = loc >= 0.f ? loc : NSLOPE * loc;   // leaky relu
    float sc = expf(ps.z + pd.w);            // exp(lsl[src] + lsr[dst])
    float ev = loc + sc * noise[e];
    ew[e] = ev;
    atomicMaxFloat(&nmax[d], ev);
}

// K3: one lane per (edge, feature): unnormalized scatter
// out[d][f] += exp(e - max[d]) * h[s][f];  nsum[d] += exp(e - max[d])
__global__ __launch_bounds__(256) void k3_scatter(
    const int* __restrict__ src, const int* __restrict__ dst,
    const float* __restrict__ ew, const float* __restrict__ nmax,
    const float* __restrict__ h, float* __restrict__ nsum,
    float* __restrict__ out, int E)
{
    long idx = (long)blockIdx.x * 256 + threadIdx.x;
    int e = (int)(idx >> 6), lane = (int)(idx & 63);
    if (e >= E) return;
    int d = dst[e];
    float ex = expf(ew[e] - nmax[d]);
    if (lane == 0) atomicAdd(&nsum[d], ex);
    int s = src[e];
    float hv = h[(long)s * 64 + lane];
    atomicAdd(&out[(long)d * 64 + lane], ex * hv);
}

// K4: normalize + bias (guard empty segments -> bias, matching 0 + bias? ref gives 0+bias)
__global__ __launch_bounds__(256) void k4_final(
    float* __restrict__ out, const float* __restrict__ nsum,
    const float* __restrict__ bias, int nf)
{
    int i = blockIdx.x * 256 + threadIdx.x;
    if (i >= nf) return;
    int n = i >> 6, f = i & 63;
    float s = nsum[n];
    out[i] = (s > 0.f) ? (out[i] / s + bias[f]) : bias[f];
}

extern "C" void kernel_launch(void* const* d_in, const int* in_sizes, int n_in,
                              void* d_out, int out_size, void* d_ws, size_t ws_size,
                              hipStream_t stream) {
    const float* feat  = (const float*)d_in[0];
    const float* wfc   = (const float*)d_in[1];
    const float* wpost = (const float*)d_in[2];
    const float* bpost = (const float*)d_in[3];
    const float* bias  = (const float*)d_in[4];
    const float* noise = (const float*)d_in[5];
    const int*   src   = (const int*)d_in[6];
    const int*   dst   = (const int*)d_in[7];
    int N = in_sizes[0] / 128;
    int E = in_sizes[6];
    float* out = (float*)d_out;

    // workspace layout (floats): h[N*64] | pp[N*4] | ew[E] | nmax[N] | nsum[N]
    float*  ws   = (float*)d_ws;
    float*  h    = ws;
    float4* pp   = (float4*)(ws + (size_t)N * 64);
    float*  ew   = ws + (size_t)N * 64 + (size_t)N * 4;
    float*  nmax = ew + E;
    float*  nsum = nmax + N;

    int NF = N * 64;
    hipLaunchKernelGGL(k0_init, dim3((NF + 255) / 256), dim3(256), 0, stream,
                       out, nmax, nsum, N, NF);
    hipLaunchKernelGGL(k1_proj, dim3((N + 15) / 16), dim3(256), 0, stream,
                       feat, wfc, wpost, bpost, h, pp, N);
    hipLaunchKernelGGL(k2_edge, dim3((E + 255) / 256), dim3(256), 0, stream,
                       src, dst, noise, pp, ew, nmax, E);
    long k3_threads = (long)E * 64;
    hipLaunchKernelGGL(k3_scatter, dim3((unsigned)((k3_threads + 255) / 256)), dim3(256), 0, stream,
                       src, dst, ew, nmax, h, nsum, out, E);
    hipLaunchKernelGGL(k4_final, dim3((NF + 255) / 256), dim3(256), 0, stream,
                       out, nsum, bias, NF);
}

// Round 2
// 519.291 us; speedup vs baseline: 1.3922x; 1.3922x over previous
//
#include <hip/hip_runtime.h>
#include <math.h>

#define NSLOPE 0.2f

// ---------------- K0: zero degree counters ----------------
__global__ __launch_bounds__(256) void k0_zero(int* __restrict__ deg, int n) {
    int i = blockIdx.x * 256 + threadIdx.x;
    if (i < n) deg[i] = 0;
}

// ---------------- K1: h = feat @ W_fc, fused pp = h @ W_post + b_post ----------------
// block = 256 threads = 4 waves; 16 rows/block (4 rows per wave); col = lane
__global__ __launch_bounds__(256) void k1_proj(
    const float* __restrict__ feat, const float* __restrict__ wfc,
    const float* __restrict__ wpost, const float* __restrict__ bpost,
    float* __restrict__ h, float4* __restrict__ pp, int n)
{
    __shared__ float wfc_s[128 * 64];   // 32 KB
    __shared__ float feat_s[16 * 128];  // 8 KB
    int t = threadIdx.x;
    for (int i = t; i < 128 * 64 / 4; i += 256)
        ((float4*)wfc_s)[i] = ((const float4*)wfc)[i];
    int row0 = blockIdx.x * 16;
    {
        const float4* fv = (const float4*)(feat + (long)row0 * 128);
        int lim = (n - row0) * (128 / 4);
        if (lim > 16 * 128 / 4) lim = 16 * 128 / 4;
        for (int i = t; i < lim; i += 256)
            ((float4*)feat_s)[i] = fv[i];
    }
    __syncthreads();
    int lane = t & 63, wv = t >> 6;
    const float* fr = feat_s + wv * 4 * 128;
    float acc[4] = {0.f, 0.f, 0.f, 0.f};
    #pragma unroll 4
    for (int k = 0; k < 128; k++) {
        float w = wfc_s[k * 64 + lane];   // 2-way alias across wave64: free
        #pragma unroll
        for (int r = 0; r < 4; r++) acc[r] += fr[r * 128 + k] * w;  // LDS broadcast
    }
    int r0 = row0 + wv * 4;
    #pragma unroll
    for (int r = 0; r < 4; r++)
        if (r0 + r < n) h[(long)(r0 + r) * 64 + lane] = acc[r];
    // pp epilogue: wave-wide reduction, lane = h-column
    float4 wp = ((const float4*)wpost)[lane];
    float4 bp = *((const float4*)bpost);
    #pragma unroll
    for (int r = 0; r < 4; r++) {
        float cx = acc[r] * wp.x, cy = acc[r] * wp.y,
              cz = acc[r] * wp.z, cw = acc[r] * wp.w;
        #pragma unroll
        for (int off = 32; off > 0; off >>= 1) {
            cx += __shfl_down(cx, off);
            cy += __shfl_down(cy, off);
            cz += __shfl_down(cz, off);
            cw += __shfl_down(cw, off);
        }
        if (lane == 0 && r0 + r < n) {
            float4 o;
            o.x = cx + bp.x; o.y = cy + bp.y; o.z = cz + bp.z; o.w = cw + bp.w;
            pp[r0 + r] = o;
        }
    }
}

// ---------------- K2: degree histogram over dst ----------------
__global__ __launch_bounds__(256) void k2_hist(const int* __restrict__ dst,
                                               int* __restrict__ deg, int E) {
    int e = blockIdx.x * 256 + threadIdx.x;
    if (e < E) atomicAdd(&deg[dst[e]], 1);
}

// ---------------- K3a/b/c: exclusive prefix scan of deg -> base ----------------
// 1024 items per block (256 threads x 4)
__global__ __launch_bounds__(256) void scan_a(const int* __restrict__ deg,
                                              int* __restrict__ base,
                                              int* __restrict__ bsum, int N) {
    __shared__ int lds[256];
    int t = threadIdx.x;
    int i0 = blockIdx.x * 1024 + t * 4;
    int d0 = (i0 + 0 < N) ? deg[i0 + 0] : 0;
    int d1 = (i0 + 1 < N) ? deg[i0 + 1] : 0;
    int d2 = (i0 + 2 < N) ? deg[i0 + 2] : 0;
    int d3 = (i0 + 3 < N) ? deg[i0 + 3] : 0;
    lds[t] = d0 + d1 + d2 + d3;
    __syncthreads();
    for (int off = 1; off < 256; off <<= 1) {   // Hillis-Steele inclusive
        int v = (t >= off) ? lds[t - off] : 0;
        __syncthreads();
        lds[t] += v;
        __syncthreads();
    }
    int excl = t ? lds[t - 1] : 0;
    if (t == 255) bsum[blockIdx.x] = lds[255];
    if (i0 + 0 < N) base[i0 + 0] = excl;
    if (i0 + 1 < N) base[i0 + 1] = excl + d0;
    if (i0 + 2 < N) base[i0 + 2] = excl + d0 + d1;
    if (i0 + 3 < N) base[i0 + 3] = excl + d0 + d1 + d2;
}

__global__ __launch_bounds__(256) void scan_b(int* __restrict__ bsum, int nb) {
    __shared__ int lds[1024];
    int t = threadIdx.x;
    for (int i = t; i < nb; i += 256) lds[i] = bsum[i];
    __syncthreads();
    if (t == 0) {
        int run = 0;
        for (int i = 0; i < nb; i++) { int v = lds[i]; lds[i] = run; run += v; }
    }
    __syncthreads();
    for (int i = t; i < nb; i += 256) bsum[i] = lds[i];
}

// add block offsets; also re-zero deg (reused as scatter cursor) and set base[N]=E
__global__ __launch_bounds__(256) void scan_c(int* __restrict__ base,
                                              const int* __restrict__ bsum,
                                              int* __restrict__ deg, int N, int E) {
    int i = blockIdx.x * 256 + threadIdx.x;
    if (i < N) { base[i] += bsum[i >> 10]; deg[i] = 0; }
    else if (i == N) base[N] = E;
}

// ---------------- K4: per-edge value + scatter into dst-sorted CSR ----------------
__global__ __launch_bounds__(256) void k4_scatter(
    const int* __restrict__ src, const int* __restrict__ dst,
    const float* __restrict__ noise, const float4* __restrict__ pp,
    const int* __restrict__ base, int* __restrict__ cur,
    float* __restrict__ sew, int* __restrict__ ssrc, int E)
{
    int e = blockIdx.x * 256 + threadIdx.x;
    if (e >= E) return;
    int s = src[e], d = dst[e];
    float4 ps = pp[s], pd = pp[d];
    float loc = ps.x + pd.y;                  // loc_l[src] + loc_r[dst]
    loc = loc >= 0.f ? loc : NSLOPE * loc;    // leaky relu
    float ev = loc + __expf(ps.z + pd.w) * noise[e];
    int pos = base[d] + atomicAdd(&cur[d], 1);
    sew[pos] = ev;
    ssrc[pos] = s;
}

// ---------------- K5: one wave per node: softmax + weighted h accumulation ----------------
__global__ __launch_bounds__(256) void k5_node(
    const int* __restrict__ base, const float* __restrict__ sew,
    const int* __restrict__ ssrc, const float* __restrict__ h,
    const float* __restrict__ bias, float* __restrict__ out, int N)
{
    int wid = (int)((blockIdx.x * 256 + threadIdx.x) >> 6);
    int lane = threadIdx.x & 63;
    if (wid >= N) return;
    int b0 = base[wid], b1 = base[wid + 1];
    float bl = bias[lane];
    long obase = (long)wid * 64 + lane;
    if (b1 == b0) { out[obase] = bl; return; }
    // pass 1: cooperative max over this node's edges
    float m = -INFINITY;
    for (int j = b0 + lane; j < b1; j += 64) m = fmaxf(m, sew[j]);
    #pragma unroll
    for (int off = 32; off > 0; off >>= 1) m = fmaxf(m, __shfl_xor(m, off));
    // pass 2: serial over edges; lanes parallel over 64 features
    float acc = 0.f, ssum = 0.f;
    for (int j = b0; j < b1; j++) {
        float w = __expf(sew[j] - m);   // uniform across wave
        int s = ssrc[j];                 // uniform across wave
        ssum += w;
        acc += w * h[(long)s * 64 + lane];   // 256B coalesced gather
    }
    out[obase] = acc / ssum + bl;
}

extern "C" void kernel_launch(void* const* d_in, const int* in_sizes, int n_in,
                              void* d_out, int out_size, void* d_ws, size_t ws_size,
                              hipStream_t stream) {
    const float* feat  = (const float*)d_in[0];
    const float* wfc   = (const float*)d_in[1];
    const float* wpost = (const float*)d_in[2];
    const float* bpost = (const float*)d_in[3];
    const float* bias  = (const float*)d_in[4];
    const float* noise = (const float*)d_in[5];
    const int*   src   = (const int*)d_in[6];
    const int*   dst   = (const int*)d_in[7];
    int N = in_sizes[0] / 128;
    int E = in_sizes[6];
    float* out = (float*)d_out;

    // workspace (floats/ints, 4B units):
    // h[N*64] | pp[N*4] | deg[N] | base[N+1] | bsum[1024] | sew[E] | ssrc[E]
    float* ws   = (float*)d_ws;
    float* h    = ws;
    float4* pp  = (float4*)(ws + (size_t)N * 64);
    int*  deg   = (int*)(ws + (size_t)N * 64 + (size_t)N * 4);
    int*  base  = deg + N;
    int*  bsum  = base + (N + 1);
    float* sew  = (float*)(bsum + 1024);
    int*  ssrc  = (int*)(sew + E);

    int nb = (N + 1023) / 1024;   // scan blocks

    hipLaunchKernelGGL(k0_zero, dim3((N + 255) / 256), dim3(256), 0, stream, deg, N);
    hipLaunchKernelGGL(k1_proj, dim3((N + 15) / 16), dim3(256), 0, stream,
                       feat, wfc, wpost, bpost, h, pp, N);
    hipLaunchKernelGGL(k2_hist, dim3((E + 255) / 256), dim3(256), 0, stream, dst, deg, E);
    hipLaunchKernelGGL(scan_a, dim3(nb), dim3(256), 0, stream, deg, base, bsum, N);
    hipLaunchKernelGGL(scan_b, dim3(1), dim3(256), 0, stream, bsum, nb);
    hipLaunchKernelGGL(scan_c, dim3((N + 256) / 256), dim3(256), 0, stream,
                       base, bsum, deg, N, E);
    hipLaunchKernelGGL(k4_scatter, dim3((E + 255) / 256), dim3(256), 0, stream,
                       src, dst, noise, pp, base, deg, sew, ssrc, E);
    long k5_threads = (long)N * 64;
    hipLaunchKernelGGL(k5_node, dim3((unsigned)((k5_threads + 255) / 256)), dim3(256), 0, stream,
                       base, sew, ssrc, h, bias, out, N);
}

// Round 3
// 449.793 us; speedup vs baseline: 1.6073x; 1.1545x over previous
//
#include <hip/hip_runtime.h>
#include <math.h>

#define NSLOPE 0.2f

__device__ __forceinline__ void atomicMaxFloat(float* addr, float val) {
    if (val >= 0.0f) atomicMax((int*)addr, __float_as_int(val));
    else             atomicMin((unsigned int*)addr, __float_as_uint(val));
}

// ---------------- K0: zero degree counters, nmax = -inf ----------------
__global__ __launch_bounds__(256) void k0_init(int* __restrict__ deg,
                                               float* __restrict__ nmax, int n) {
    int i = blockIdx.x * 256 + threadIdx.x;
    if (i < n) { deg[i] = 0; nmax[i] = -INFINITY; }
}

// ---------------- K1: h = feat @ W_fc, fused pp = h @ W_post + b_post ----------------
__global__ __launch_bounds__(256) void k1_proj(
    const float* __restrict__ feat, const float* __restrict__ wfc,
    const float* __restrict__ wpost, const float* __restrict__ bpost,
    float* __restrict__ h, float4* __restrict__ pp, int n)
{
    __shared__ float wfc_s[128 * 64];   // 32 KB
    __shared__ float feat_s[16 * 128];  // 8 KB
    int t = threadIdx.x;
    for (int i = t; i < 128 * 64 / 4; i += 256)
        ((float4*)wfc_s)[i] = ((const float4*)wfc)[i];
    int row0 = blockIdx.x * 16;
    {
        const float4* fv = (const float4*)(feat + (long)row0 * 128);
        int lim = (n - row0) * (128 / 4);
        if (lim > 16 * 128 / 4) lim = 16 * 128 / 4;
        for (int i = t; i < lim; i += 256)
            ((float4*)feat_s)[i] = fv[i];
    }
    __syncthreads();
    int lane = t & 63, wv = t >> 6;
    const float* fr = feat_s + wv * 4 * 128;
    float acc[4] = {0.f, 0.f, 0.f, 0.f};
    #pragma unroll 4
    for (int k = 0; k < 128; k++) {
        float w = wfc_s[k * 64 + lane];   // 2-way alias across wave64: free
        #pragma unroll
        for (int r = 0; r < 4; r++) acc[r] += fr[r * 128 + k] * w;  // LDS broadcast
    }
    int r0 = row0 + wv * 4;
    #pragma unroll
    for (int r = 0; r < 4; r++)
        if (r0 + r < n) h[(long)(r0 + r) * 64 + lane] = acc[r];
    // pp epilogue: wave-wide reduction, lane = h-column
    float4 wp = ((const float4*)wpost)[lane];
    float4 bp = *((const float4*)bpost);
    #pragma unroll
    for (int r = 0; r < 4; r++) {
        float cx = acc[r] * wp.x, cy = acc[r] * wp.y,
              cz = acc[r] * wp.z, cw = acc[r] * wp.w;
        #pragma unroll
        for (int off = 32; off > 0; off >>= 1) {
            cx += __shfl_down(cx, off);
            cy += __shfl_down(cy, off);
            cz += __shfl_down(cz, off);
            cw += __shfl_down(cw, off);
        }
        if (lane == 0 && r0 + r < n) {
            float4 o;
            o.x = cx + bp.x; o.y = cy + bp.y; o.z = cz + bp.z; o.w = cw + bp.w;
            pp[r0 + r] = o;
        }
    }
}

// ---------------- K2: degree histogram over dst ----------------
__global__ __launch_bounds__(256) void k2_hist(const int* __restrict__ dst,
                                               int* __restrict__ deg, int E) {
    int e = blockIdx.x * 256 + threadIdx.x;
    if (e < E) atomicAdd(&deg[dst[e]], 1);
}

// ---------------- scan: exclusive prefix of deg -> base ----------------
__global__ __launch_bounds__(256) void scan_a(const int* __restrict__ deg,
                                              int* __restrict__ base,
                                              int* __restrict__ bsum, int N) {
    __shared__ int lds[256];
    int t = threadIdx.x;
    int i0 = blockIdx.x * 1024 + t * 4;
    int d0 = (i0 + 0 < N) ? deg[i0 + 0] : 0;
    int d1 = (i0 + 1 < N) ? deg[i0 + 1] : 0;
    int d2 = (i0 + 2 < N) ? deg[i0 + 2] : 0;
    int d3 = (i0 + 3 < N) ? deg[i0 + 3] : 0;
    lds[t] = d0 + d1 + d2 + d3;
    __syncthreads();
    for (int off = 1; off < 256; off <<= 1) {
        int v = (t >= off) ? lds[t - off] : 0;
        __syncthreads();
        lds[t] += v;
        __syncthreads();
    }
    int excl = t ? lds[t - 1] : 0;
    if (t == 255) bsum[blockIdx.x] = lds[255];
    if (i0 + 0 < N) base[i0 + 0] = excl;
    if (i0 + 1 < N) base[i0 + 1] = excl + d0;
    if (i0 + 2 < N) base[i0 + 2] = excl + d0 + d1;
    if (i0 + 3 < N) base[i0 + 3] = excl + d0 + d1 + d2;
}

__global__ __launch_bounds__(256) void scan_b(int* __restrict__ bsum, int nb) {
    __shared__ int lds[1024];
    int t = threadIdx.x;
    for (int i = t; i < nb; i += 256) lds[i] = bsum[i];
    __syncthreads();
    if (t == 0) {
        int run = 0;
        for (int i = 0; i < nb; i++) { int v = lds[i]; lds[i] = run; run += v; }
    }
    __syncthreads();
    for (int i = t; i < nb; i += 256) bsum[i] = lds[i];
}

__global__ __launch_bounds__(256) void scan_c(int* __restrict__ base,
                                              const int* __restrict__ bsum,
                                              int* __restrict__ deg, int N, int E) {
    int i = blockIdx.x * 256 + threadIdx.x;
    if (i < N) { base[i] += bsum[i >> 10]; deg[i] = 0; }
    else if (i == N) base[N] = E;
}

// ---------------- K4: edge value + packed scatter into dst-sorted CSR + seg-max ----------------
__global__ __launch_bounds__(256) void k4_scatter(
    const int* __restrict__ src, const int* __restrict__ dst,
    const float* __restrict__ noise, const float4* __restrict__ pp,
    const int* __restrict__ base, int* __restrict__ cur,
    float* __restrict__ nmax, float2* __restrict__ ed, int E)
{
    int e = blockIdx.x * 256 + threadIdx.x;
    if (e >= E) return;
    int s = src[e], d = dst[e];
    float4 ps = pp[s], pd = pp[d];
    float loc = ps.x + pd.y;                  // loc_l[src] + loc_r[dst]
    loc = loc >= 0.f ? loc : NSLOPE * loc;    // leaky relu
    float ev = loc + __expf(ps.z + pd.w) * noise[e];
    int pos = base[d] + atomicAdd(&cur[d], 1);
    float2 v; v.x = ev; v.y = __int_as_float(s);
    ed[pos] = v;                              // single 8B scattered store
    atomicMaxFloat(&nmax[d], ev);
}

// ---------------- K5: one wave per node, 4 edges in flight ----------------
__global__ __launch_bounds__(256) void k5_node(
    const int* __restrict__ base, const float2* __restrict__ ed,
    const float* __restrict__ nmax, const float* __restrict__ h,
    const float* __restrict__ bias, float* __restrict__ out, int N)
{
    int wid = (int)((blockIdx.x * 256 + threadIdx.x) >> 6);
    int lane = threadIdx.x & 63;
    if (wid >= N) return;
    int b0 = base[wid], b1 = base[wid + 1];
    float bl = bias[lane];
    long ob = (long)wid * 64 + lane;
    if (b1 == b0) { out[ob] = bl; return; }
    float m = nmax[wid];
    float acc = 0.f, ssum = 0.f;
    int j = b0;
    for (; j + 4 <= b1; j += 4) {
        float2 e0 = ed[j], e1 = ed[j + 1], e2 = ed[j + 2], e3 = ed[j + 3];
        // 4 independent 256B row gathers in flight
        float v0 = h[(long)__float_as_int(e0.y) * 64 + lane];
        float v1 = h[(long)__float_as_int(e1.y) * 64 + lane];
        float v2 = h[(long)__float_as_int(e2.y) * 64 + lane];
        float v3 = h[(long)__float_as_int(e3.y) * 64 + lane];
        float w0 = __expf(e0.x - m), w1 = __expf(e1.x - m),
              w2 = __expf(e2.x - m), w3 = __expf(e3.x - m);
        ssum += (w0 + w1) + (w2 + w3);
        acc += w0 * v0; acc += w1 * v1; acc += w2 * v2; acc += w3 * v3;
    }
    for (; j < b1; j++) {
        float2 e = ed[j];
        float w = __expf(e.x - m);
        ssum += w;
        acc += w * h[(long)__float_as_int(e.y) * 64 + lane];
    }
    out[ob] = acc / ssum + bl;
}

extern "C" void kernel_launch(void* const* d_in, const int* in_sizes, int n_in,
                              void* d_out, int out_size, void* d_ws, size_t ws_size,
                              hipStream_t stream) {
    const float* feat  = (const float*)d_in[0];
    const float* wfc   = (const float*)d_in[1];
    const float* wpost = (const float*)d_in[2];
    const float* bpost = (const float*)d_in[3];
    const float* bias  = (const float*)d_in[4];
    const float* noise = (const float*)d_in[5];
    const int*   src   = (const int*)d_in[6];
    const int*   dst   = (const int*)d_in[7];
    int N = in_sizes[0] / 128;
    int E = in_sizes[6];
    float* out = (float*)d_out;

    // ws layout (4B units), ed first for 8/16B alignment:
    // ed[2E] | h[N*64] | pp[N*4] | deg[N] | base[N+1] | bsum[1024] | nmax[N]
    float*  ws   = (float*)d_ws;
    float2* ed   = (float2*)ws;
    float*  h    = ws + (size_t)2 * E;
    float4* pp   = (float4*)(h + (size_t)N * 64);
    int*    deg  = (int*)(h + (size_t)N * 64 + (size_t)N * 4);
    int*    base = deg + N;
    int*    bsum = base + (N + 1);
    float*  nmax = (float*)(bsum + 1024);

    int nb = (N + 1023) / 1024;

    hipLaunchKernelGGL(k0_init, dim3((N + 255) / 256), dim3(256), 0, stream, deg, nmax, N);
    hipLaunchKernelGGL(k1_proj, dim3((N + 15) / 16), dim3(256), 0, stream,
                       feat, wfc, wpost, bpost, h, pp, N);
    hipLaunchKernelGGL(k2_hist, dim3((E + 255) / 256), dim3(256), 0, stream, dst, deg, E);
    hipLaunchKernelGGL(scan_a, dim3(nb), dim3(256), 0, stream, deg, base, bsum, N);
    hipLaunchKernelGGL(scan_b, dim3(1), dim3(256), 0, stream, bsum, nb);
    hipLaunchKernelGGL(scan_c, dim3((N + 256) / 256), dim3(256), 0, stream,
                       base, bsum, deg, N, E);
    hipLaunchKernelGGL(k4_scatter, dim3((E + 255) / 256), dim3(256), 0, stream,
                       src, dst, noise, pp, base, deg, nmax, ed, E);
    long k5_threads = (long)N * 64;
    hipLaunchKernelGGL(k5_node, dim3((unsigned)((k5_threads + 255) / 256)), dim3(256), 0, stream,
                       base, ed, nmax, h, bias, out, N);
}